// Round 3
// baseline (585.071 us; speedup 1.0000x reference)
//
#include <hip/hip_runtime.h>

#define HID    128
#define GATES  512      // 4*HID
#define EMB    64
#define TSTEPS 1024
#define BATCH  512
#define VOCAB  50257
#define NCLS   28
#define H8STRIDE 160    // h row stride in BYTES (i8 h)
#define TPAD   8        // token row pad (ints)
#define TTAIL  4        // token tail pad: prefetch never needs a clamp

// gate pre-scale folded into proj and w_hh scales: i,f,o -> -log2e; g -> -2log2e
#define S_SIG  (-1.442695041f)
#define S_TANH (-2.885390082f)

typedef __attribute__((ext_vector_type(8))) short short8;   // 8 bf16 = 4 VGPRs
typedef __attribute__((ext_vector_type(4))) float f32x4;
typedef __attribute__((ext_vector_type(4))) unsigned short us4;
typedef __attribute__((ext_vector_type(4))) int int4v;
typedef __attribute__((ext_vector_type(2))) int int2v;

// lgkm-only barrier: LDS visibility without draining global (vmcnt) loads.
#define BAR_LGKM() __asm__ __volatile__("s_waitcnt lgkmcnt(0)\n\ts_barrier" ::: "memory")

static __device__ __forceinline__ float bf2f(unsigned short u){
  union { unsigned int i; float f; } v; v.i = ((unsigned int)u) << 16; return v.f;
}
static __device__ __forceinline__ unsigned short f2bf(float f){
  union { float ff; unsigned int i; } v; v.ff = f;
  unsigned int x = v.i;
  x += 0x7fffu + ((x >> 16) & 1u);   // round-to-nearest-even
  return (unsigned short)(x >> 16);
}

// ---------------------------------------------------------------------------
// Phase 1: proj[v][hcol*4+type] = s_type*(emb[v].w_ih[g] + bias[g]),
// g = type*128 + hcol. 64 vrows/block, 4 waves; operand roles swapped:
//   A (C-rows, m: type=m&3, hcol=hc+(m>>2)) = w_ih rows, B (C-cols) = emb rows.
// Lane's 4 acc regs = the 4 types of one (v,hcol) -> contiguous us4 store,
// no LDS stage, no syncthreads; w_ih conversion amortized over 4 v-tiles.
// Split-bf16 (hi/lo) 3-MFMA product preserved for accuracy.
// (unchanged from the 442.8 µs passing version)
// ---------------------------------------------------------------------------
__global__ __launch_bounds__(256) void emb_proj_kernel(
    const float* __restrict__ emb,     // [V][64]
    const float* __restrict__ w_ih,    // [512][64]
    const float* __restrict__ b_ih,    // [512]
    const float* __restrict__ b_hh,    // [512]
    unsigned short* __restrict__ proj) // [V][512] interleaved bf16
{
  int wave = threadIdx.x >> 6;         // 0..3
  int lane = threadIdx.x & 63;
  int n = lane & 15;
  int q = lane >> 4;
  long v0 = (long)blockIdx.x * 64;

  // B-operand: emb rows for 4 v-tiles (C-col n -> vrow v0+vt*16+n), split bf16
  short8 bhi[4][2], blo[4][2];
  #pragma unroll
  for (int vt = 0; vt < 4; ++vt){
    long vrow = v0 + vt * 16 + n; if (vrow >= VOCAB) vrow = VOCAB - 1;
    const float* er = emb + vrow * EMB;
    #pragma unroll
    for (int ch = 0; ch < 2; ++ch){
      f32x4 e0 = *(const f32x4*)(er + ch * 32 + q * 8);
      f32x4 e1 = *(const f32x4*)(er + ch * 32 + q * 8 + 4);
      #pragma unroll
      for (int j = 0; j < 4; ++j){
        unsigned short h0 = f2bf(e0[j]);
        bhi[vt][ch][j] = (short)h0;
        blo[vt][ch][j] = (short)f2bf(e0[j] - bf2f(h0));
        unsigned short h1 = f2bf(e1[j]);
        bhi[vt][ch][j + 4] = (short)h1;
        blo[vt][ch][j + 4] = (short)f2bf(e1[j] - bf2f(h1));
      }
    }
  }

  #pragma unroll 1
  for (int i = 0; i < 8; ++i){
    int hc = (wave * 8 + i) * 4;       // hcol group base (4 hcols x 4 types)
    // A-operand: lane n supplies matrix row m=n: gate = (n&3)*128 + hc + (n>>2)
    const float* wr = w_ih + (long)((n & 3) * 128 + hc + (n >> 2)) * EMB;
    short8 ahi[2], alo[2];
    #pragma unroll
    for (int ch = 0; ch < 2; ++ch){
      f32x4 w0 = *(const f32x4*)(wr + ch * 32 + q * 8);
      f32x4 w1 = *(const f32x4*)(wr + ch * 32 + q * 8 + 4);
      #pragma unroll
      for (int j = 0; j < 4; ++j){
        unsigned short h0 = f2bf(w0[j]);
        ahi[ch][j] = (short)h0;
        alo[ch][j] = (short)f2bf(w0[j] - bf2f(h0));
        unsigned short h1 = f2bf(w1[j]);
        ahi[ch][j + 4] = (short)h1;
        alo[ch][j + 4] = (short)f2bf(w1[j] - bf2f(h1));
      }
    }
    // bias for this lane's C rows: acc reg r -> gate r*128 + hc + q
    f32x4 bias;
    #pragma unroll
    for (int r = 0; r < 4; ++r){
      int g = r * 128 + hc + q;
      bias[r] = b_ih[g] + b_hh[g];
    }
    #pragma unroll
    for (int vt = 0; vt < 4; ++vt){
      f32x4 acc = bias;
      #pragma unroll
      for (int ch = 0; ch < 2; ++ch){
        acc = __builtin_amdgcn_mfma_f32_16x16x32_bf16(ahi[ch], bhi[vt][ch], acc, 0, 0, 0);
        acc = __builtin_amdgcn_mfma_f32_16x16x32_bf16(ahi[ch], blo[vt][ch], acc, 0, 0, 0);
        acc = __builtin_amdgcn_mfma_f32_16x16x32_bf16(alo[ch], bhi[vt][ch], acc, 0, 0, 0);
      }
      long v = v0 + vt * 16 + n;
      if (v < VOCAB){
        us4 o;
        #pragma unroll
        for (int r = 0; r < 4; ++r)
          o[r] = f2bf(((r == 2) ? S_TANH : S_SIG) * acc[r]);
        *(us4*)(proj + v * GATES + (hc + q) * 4) = o;   // 8B contiguous store
      }
    }
  }
}

// ---------------------------------------------------------------------------
// Phase 2 (restructured): 512 blocks x 256 threads (4 waves), ONE row/block ->
// 2 independent blocks per CU. Same 8 waves/CU as before, but two barrier
// domains: the blocks drift anti-phase, so one block's nonlin overlaps the
// other's LDS-read/MFMA (the ~50% idle in the lockstep 8-wave version).
// Per wave: 8 gate-tiles (hg=0,1 hcol-groups x 4 types), 16 MFMAs/substep
// (chunk pairs independent ZERO-C + int add). Lane (n,q) selects its
// hcol-group by hg=q>>1 -> nonlin stays 1 hcol/lane (2x dup, same as before).
// A-operand = single row h (all 16 MFMA rows dup). One lgkm barrier/substep.
// ---------------------------------------------------------------------------
__global__ __launch_bounds__(256, 2) void lstm_kernel(
    const int* __restrict__ x,           // [512][1024] int32
    const float* __restrict__ w_hh,      // [512][128] f32
    const unsigned short* __restrict__ proj, // [V][512] bf16 interleaved
    const float* __restrict__ w_lin,     // [28][128] f32
    const float* __restrict__ b_lin,     // [28] f32
    float* __restrict__ out)             // [512][28] f32
{
  __shared__ int   tok_lds[TSTEPS + TPAD];   // tok*GATES*2 (byte offsets)
  __shared__ signed char h8[2][H8STRIDE];    // [buf][hcol] i8 h (1 row)

  int tid  = threadIdx.x;
  int wave = tid >> 6;          // 0..3
  int lane = tid & 63;
  int n = lane & 15;
  int q = lane >> 4;
  int r = blockIdx.x;           // batch row (R=1)

  // --- preload tokens (pre-multiplied BYTE offsets into proj) -----------
  for (int i = tid; i < TSTEPS + TTAIL; i += 256){
    int src = i < TSTEPS ? i : TSTEPS - 1;
    tok_lds[i] = x[(long)r * TSTEPS + src] * (GATES * 2);
  }

  // --- quantize w_hh to i8, per-gate-row max scale ----------------------
  // tile t = hg*4 + type: gate row g = type*128 + wave*32 + hg*16 + n;
  // B[k = ch*64 + q*16 + j][n] = w_q[g][k]
  int4v Bw[8][2];
  float scl[8];
  #pragma unroll
  for (int t = 0; t < 8; ++t){
    int type = t & 3, hgt = t >> 2;
    int row = type * 128 + wave * 32 + hgt * 16 + n;
    const float* wr = w_hh + (long)row * HID;
    float vals[2][16];
    float m = 0.f;
    #pragma unroll
    for (int ch = 0; ch < 2; ++ch)
      #pragma unroll
      for (int j = 0; j < 16; ++j){
        float v = wr[ch * 64 + q * 16 + j];
        vals[ch][j] = v;
        m = fmaxf(m, fabsf(v));
      }
    m = fmaxf(m, __shfl_xor(m, 16, 64));
    m = fmaxf(m, __shfl_xor(m, 32, 64));
    m = fmaxf(m, 1e-20f);
    float qs = 127.f / m;
    #pragma unroll
    for (int ch = 0; ch < 2; ++ch){
      #pragma unroll
      for (int d = 0; d < 4; ++d){
        int b0 = (int)__builtin_rintf(vals[ch][d * 4 + 0] * qs);
        int b1 = (int)__builtin_rintf(vals[ch][d * 4 + 1] * qs);
        int b2 = (int)__builtin_rintf(vals[ch][d * 4 + 2] * qs);
        int b3 = (int)__builtin_rintf(vals[ch][d * 4 + 3] * qs);
        Bw[t][ch][d] = (b0 & 255) | ((b1 & 255) << 8) | ((b2 & 255) << 16) | (b3 << 24);
      }
    }
    scl[t] = ((type == 2) ? S_TANH : S_SIG) * m * (1.f / 16129.f);  // /127^2
  }

  // per-lane hcol-group select (loop-invariant)
  int hg = (q >> 1) & 1;
  float sclS0 = hg ? scl[4] : scl[0];
  float sclS1 = hg ? scl[5] : scl[1];
  float sclS2 = hg ? scl[6] : scl[2];
  float sclS3 = hg ? scl[7] : scl[3];

  // zero h buffers (h0 = 0)
  for (int i = tid; i < 2 * H8STRIDE; i += 256) ((signed char*)h8)[i] = 0;

  float c_state = 0.f;                   // dup pairs (q, q^1) identical
  int   hcol  = wave * 32 + hg * 16 + n; // this lane's hcol
  const int4v ZERO4 = {0, 0, 0, 0};      // loop-invariant MFMA C operand
  int ghcolB = hcol * 8;                 // byte offset within a proj row

  __syncthreads();                       // tokens + h zeros

  // --- depth-2 gx prefetch ----------------------------------------------
  us4 hxA, hxB;
  hxA = *(const us4*)((const char*)proj + (unsigned)(tok_lds[0] + ghcolB));
  hxB = *(const us4*)((const char*)proj + (unsigned)(tok_lds[1] + ghcolB));

#define MFMA8(AF0, AF1, T) \
  (__builtin_amdgcn_mfma_i32_16x16x64_i8(AF0, Bw[T][0], ZERO4, 0, 0, 0)[0] + \
   __builtin_amdgcn_mfma_i32_16x16x64_i8(AF1, Bw[T][1], ZERO4, 0, 0, 0)[0])

#define SUBSTEP(RB, HX, TOKB)                                                 \
  {                                                                           \
    int4v Af0 = *(const int4v*)(&h8[RB][q * 16]);                             \
    int4v Af1 = *(const int4v*)(&h8[RB][64 + q * 16]);                        \
    /* hoist gx bf16->f32 off the dequant chain */                            \
    float gx0 = bf2f(HX[0]), gx1 = bf2f(HX[1]);                               \
    float gx2 = bf2f(HX[2]), gx3 = bf2f(HX[3]);                               \
    HX = *(const us4*)((const char*)proj + (unsigned)((TOKB) + ghcolB));      \
    /* f-gate tiles first: c_state needs sf earliest */                       \
    int vf = hg ? MFMA8(Af0, Af1, 5) : 0;                                     \
    int vf0 = hg ? 0 : MFMA8(Af0, Af1, 1);                                    \
    vf += vf0;                                                                \
    float g1 = (float)vf * sclS1 + gx1;                                       \
    float ef = __builtin_amdgcn_exp2f(g1);                                    \
    float sf = __builtin_amdgcn_rcpf(1.f + ef);                               \
    int vi0 = MFMA8(Af0, Af1, 0);                                             \
    int vi1 = MFMA8(Af0, Af1, 4);                                             \
    int vi = hg ? vi1 : vi0;                                                  \
    float g0 = (float)vi * sclS0 + gx0;                                       \
    float ei = __builtin_amdgcn_exp2f(g0);                                    \
    int vg0 = MFMA8(Af0, Af1, 2);                                             \
    int vg1 = MFMA8(Af0, Af1, 6);                                             \
    int vg = hg ? vg1 : vg0;                                                  \
    float g2 = (float)vg * sclS2 + gx2;                                       \
    float eg = __builtin_amdgcn_exp2f(fminf(g2, 126.f));                      \
    int vo0 = MFMA8(Af0, Af1, 3);                                             \
    int vo1 = MFMA8(Af0, Af1, 7);                                             \
    int vo = hg ? vo1 : vo0;                                                  \
    float g3 = (float)vo * sclS3 + gx3;                                       \
    float eo = __builtin_amdgcn_exp2f(g3);                                    \
    float r1 = __builtin_amdgcn_rcpf((1.f + ei) * (1.f + eg));                \
    float sitg = (1.f - eg) * r1;             /* si * tg */                   \
    c_state = sf * c_state + sitg;                                            \
    float ec = __builtin_amdgcn_exp2f(fminf(S_TANH * c_state, 126.f));        \
    float r2 = __builtin_amdgcn_rcpf((1.f + eo) * (1.f + ec));                \
    float hv = (1.f - ec) * r2;               /* tanh(c) * so */              \
    /* magic-constant RNE quant: low byte of (hv*127 + 1.5*2^23) */           \
    float qf = __builtin_fmaf(hv, 127.f, 12582912.f);                         \
    h8[(RB) ^ 1][hcol] = (signed char)__float_as_uint(qf);                    \
    BAR_LGKM();                                                               \
  }

  // NOTE: the f-tile pair above uses hg-gated evaluation; both sides still
  // compute (ternary on int), matching the vi/vg/vo pattern semantics.
  for (int step = 0; step < TSTEPS; step += 2){
    int2v tk = *(const int2v*)(&tok_lds[step + 2]);   // both substeps' toks
    SUBSTEP(0, hxA, tk[0])
    SUBSTEP(1, hxB, tk[1])
  }
#undef SUBSTEP
#undef MFMA8

  // --- final linear: out[r][j] = (qh/127) . w_lin[j] + b_lin[j] ---------
  // TSTEPS even -> final h is in h8[0]
  if (tid < NCLS){
    float s = 0.f;
    const float* wl = w_lin + (long)tid * HID;
    #pragma unroll 4
    for (int k = 0; k < HID; ++k)
      s += (float)h8[0][k] * wl[k];
    out[(long)r * NCLS + tid] = b_lin[tid] + s * (1.f / 127.f);
  }
}

// ---------------------------------------------------------------------------
extern "C" void kernel_launch(void* const* d_in, const int* in_sizes, int n_in,
                              void* d_out, int out_size, void* d_ws, size_t ws_size,
                              hipStream_t stream)
{
  const int*   x     = (const int*)d_in[0];
  const float* emb   = (const float*)d_in[1];
  const float* w_ih  = (const float*)d_in[2];
  const float* w_hh  = (const float*)d_in[3];
  const float* b_ih  = (const float*)d_in[4];
  const float* b_hh  = (const float*)d_in[5];
  const float* w_lin = (const float*)d_in[6];
  const float* b_lin = (const float*)d_in[7];
  float*       out   = (float*)d_out;
  unsigned short* proj = (unsigned short*)d_ws;   // [V][512] bf16, ~51.5 MB

  int vblocks = (VOCAB + 63) / 64;   // 786
  emb_proj_kernel<<<dim3(vblocks), dim3(256), 0, stream>>>(
      emb, w_ih, b_ih, b_hh, proj);
  lstm_kernel<<<dim3(BATCH), dim3(256), 0, stream>>>(
      x, w_hh, proj, w_lin, b_lin, out);
}

// Round 4
// 398.801 us; speedup vs baseline: 1.4671x; 1.4671x over previous
//
#include <hip/hip_runtime.h>

#define HID    128
#define GATES  512      // 4*HID
#define EMB    64
#define TSTEPS 1024
#define BATCH  512
#define VOCAB  50257
#define NCLS   28
#define H8STRIDE 160    // h row stride in BYTES (i8 h)
#define TPAD   8        // token row pad (ints)
#define TTAIL  4        // token tail pad: prefetch never needs a clamp

// gate pre-scale folded into proj and w_hh scales: i,f,o -> -log2e; g -> -2log2e
#define S_SIG  (-1.442695041f)
#define S_TANH (-2.885390082f)

typedef __attribute__((ext_vector_type(8))) short short8;   // 8 bf16 = 4 VGPRs
typedef __attribute__((ext_vector_type(4))) float f32x4;
typedef __attribute__((ext_vector_type(4))) unsigned short us4;
typedef __attribute__((ext_vector_type(4))) int int4v;
typedef __attribute__((ext_vector_type(2))) int int2v;

// lgkm-only barrier: LDS visibility without draining global (vmcnt) loads.
#define BAR_LGKM() __asm__ __volatile__("s_waitcnt lgkmcnt(0)\n\ts_barrier" ::: "memory")

static __device__ __forceinline__ float bf2f(unsigned short u){
  union { unsigned int i; float f; } v; v.i = ((unsigned int)u) << 16; return v.f;
}
static __device__ __forceinline__ unsigned short f2bf(float f){
  union { float ff; unsigned int i; } v; v.ff = f;
  unsigned int x = v.i;
  x += 0x7fffu + ((x >> 16) & 1u);   // round-to-nearest-even
  return (unsigned short)(x >> 16);
}

// ---------------------------------------------------------------------------
// Phase 1: proj[v][hcol*4+type] = s_type*(emb[v].w_ih[g] + bias[g]),
// g = type*128 + hcol. 64 vrows/block, 4 waves; operand roles swapped:
//   A (C-rows, m: type=m&3, hcol=hc+(m>>2)) = w_ih rows, B (C-cols) = emb rows.
// (byte-identical to the 442.8 µs passing version)
// ---------------------------------------------------------------------------
__global__ __launch_bounds__(256) void emb_proj_kernel(
    const float* __restrict__ emb,     // [V][64]
    const float* __restrict__ w_ih,    // [512][64]
    const float* __restrict__ b_ih,    // [512]
    const float* __restrict__ b_hh,    // [512]
    unsigned short* __restrict__ proj) // [V][512] interleaved bf16
{
  int wave = threadIdx.x >> 6;         // 0..3
  int lane = threadIdx.x & 63;
  int n = lane & 15;
  int q = lane >> 4;
  long v0 = (long)blockIdx.x * 64;

  // B-operand: emb rows for 4 v-tiles (C-col n -> vrow v0+vt*16+n), split bf16
  short8 bhi[4][2], blo[4][2];
  #pragma unroll
  for (int vt = 0; vt < 4; ++vt){
    long vrow = v0 + vt * 16 + n; if (vrow >= VOCAB) vrow = VOCAB - 1;
    const float* er = emb + vrow * EMB;
    #pragma unroll
    for (int ch = 0; ch < 2; ++ch){
      f32x4 e0 = *(const f32x4*)(er + ch * 32 + q * 8);
      f32x4 e1 = *(const f32x4*)(er + ch * 32 + q * 8 + 4);
      #pragma unroll
      for (int j = 0; j < 4; ++j){
        unsigned short h0 = f2bf(e0[j]);
        bhi[vt][ch][j] = (short)h0;
        blo[vt][ch][j] = (short)f2bf(e0[j] - bf2f(h0));
        unsigned short h1 = f2bf(e1[j]);
        bhi[vt][ch][j + 4] = (short)h1;
        blo[vt][ch][j + 4] = (short)f2bf(e1[j] - bf2f(h1));
      }
    }
  }

  #pragma unroll 1
  for (int i = 0; i < 8; ++i){
    int hc = (wave * 8 + i) * 4;       // hcol group base (4 hcols x 4 types)
    // A-operand: lane n supplies matrix row m=n: gate = (n&3)*128 + hc + (n>>2)
    const float* wr = w_ih + (long)((n & 3) * 128 + hc + (n >> 2)) * EMB;
    short8 ahi[2], alo[2];
    #pragma unroll
    for (int ch = 0; ch < 2; ++ch){
      f32x4 w0 = *(const f32x4*)(wr + ch * 32 + q * 8);
      f32x4 w1 = *(const f32x4*)(wr + ch * 32 + q * 8 + 4);
      #pragma unroll
      for (int j = 0; j < 4; ++j){
        unsigned short h0 = f2bf(w0[j]);
        ahi[ch][j] = (short)h0;
        alo[ch][j] = (short)f2bf(w0[j] - bf2f(h0));
        unsigned short h1 = f2bf(w1[j]);
        ahi[ch][j + 4] = (short)h1;
        alo[ch][j + 4] = (short)f2bf(w1[j] - bf2f(h1));
      }
    }
    // bias for this lane's C rows: acc reg r -> gate r*128 + hc + q
    f32x4 bias;
    #pragma unroll
    for (int r = 0; r < 4; ++r){
      int g = r * 128 + hc + q;
      bias[r] = b_ih[g] + b_hh[g];
    }
    #pragma unroll
    for (int vt = 0; vt < 4; ++vt){
      f32x4 acc = bias;
      #pragma unroll
      for (int ch = 0; ch < 2; ++ch){
        acc = __builtin_amdgcn_mfma_f32_16x16x32_bf16(ahi[ch], bhi[vt][ch], acc, 0, 0, 0);
        acc = __builtin_amdgcn_mfma_f32_16x16x32_bf16(ahi[ch], blo[vt][ch], acc, 0, 0, 0);
        acc = __builtin_amdgcn_mfma_f32_16x16x32_bf16(alo[ch], bhi[vt][ch], acc, 0, 0, 0);
      }
      long v = v0 + vt * 16 + n;
      if (v < VOCAB){
        us4 o;
        #pragma unroll
        for (int r = 0; r < 4; ++r)
          o[r] = f2bf(((r == 2) ? S_TANH : S_SIG) * acc[r]);
        *(us4*)(proj + v * GATES + (hc + q) * 4) = o;   // 8B contiguous store
      }
    }
  }
}

// ---------------------------------------------------------------------------
// Phase 2 (v4): 256 blocks x 256 threads (4 waves), R=2 rows/block ->
// 1 block/CU, 1 wave/SIMD. MFMA/CU/substep stays 64 (= champion) but VALU
// and trans issue per SIMD halve, and nonlin duplication drops 2x -> 1x:
// lane (n,q) owns (row = q&1, hcol = wave*32 + (q>>1)*16 + n). Each wave
// covers 2 hcol-groups (hg) x 4 types x 2 K-chunks = 16 MFMAs/substep,
// ZERO-C first chunk + C-chained second at issue distance 2 (no pipe bubble).
// Lane selects its hg's result via cndmask. __launch_bounds__(256,1) lifts
// the VGPR cap (R3's spill killer). One lgkm barrier/substep.
// ---------------------------------------------------------------------------
__global__ __launch_bounds__(256, 1) void lstm_kernel(
    const int* __restrict__ x,           // [512][1024] int32
    const float* __restrict__ w_hh,      // [512][128] f32
    const unsigned short* __restrict__ proj, // [V][512] bf16 interleaved
    const float* __restrict__ w_lin,     // [28][128] f32
    const float* __restrict__ b_lin,     // [28] f32
    float* __restrict__ out)             // [512][28] f32
{
  __shared__ int   tok_lds[2][TSTEPS + TPAD];   // tok*GATES*2 (byte offsets)
  __shared__ signed char h8[2][2][H8STRIDE];    // [buf][row][hcol] i8 h

  int tid  = threadIdx.x;
  int wave = tid >> 6;          // 0..3
  int lane = tid & 63;
  int n = lane & 15;
  int q = lane >> 4;
  int r0 = blockIdx.x * 2;

  // --- preload tokens (pre-multiplied BYTE offsets into proj) -----------
  for (int i = tid; i < TSTEPS + TTAIL; i += 256){
    int src = i < TSTEPS ? i : TSTEPS - 1;
    tok_lds[0][i] = x[(long)r0 * TSTEPS + src] * (GATES * 2);
    tok_lds[1][i] = x[(long)(r0 + 1) * TSTEPS + src] * (GATES * 2);
  }

  // --- quantize w_hh to i8, per-gate-row max scale ----------------------
  // tile t = hg*4 + type: gate row = type*128 + wave*32 + hg*16 + n;
  // B[k = ch*64 + q*16 + j][col n]
  int4v Bw[8][2];
  float sclA[8];
  #pragma unroll
  for (int t = 0; t < 8; ++t){
    int type = t & 3, hgt = t >> 2;
    int row = type * 128 + wave * 32 + hgt * 16 + n;
    const float* wr = w_hh + (long)row * HID;
    float vals[2][16];
    float m = 0.f;
    #pragma unroll
    for (int ch = 0; ch < 2; ++ch)
      #pragma unroll
      for (int j = 0; j < 16; ++j){
        float v = wr[ch * 64 + q * 16 + j];
        vals[ch][j] = v;
        m = fmaxf(m, fabsf(v));
      }
    m = fmaxf(m, __shfl_xor(m, 16, 64));
    m = fmaxf(m, __shfl_xor(m, 32, 64));
    m = fmaxf(m, 1e-20f);
    float qs = 127.f / m;
    #pragma unroll
    for (int ch = 0; ch < 2; ++ch){
      #pragma unroll
      for (int d = 0; d < 4; ++d){
        int b0 = (int)__builtin_rintf(vals[ch][d * 4 + 0] * qs);
        int b1 = (int)__builtin_rintf(vals[ch][d * 4 + 1] * qs);
        int b2 = (int)__builtin_rintf(vals[ch][d * 4 + 2] * qs);
        int b3 = (int)__builtin_rintf(vals[ch][d * 4 + 3] * qs);
        Bw[t][ch][d] = (b0 & 255) | ((b1 & 255) << 8) | ((b2 & 255) << 16) | (b3 << 24);
      }
    }
    sclA[t] = ((type == 2) ? S_TANH : S_SIG) * m * (1.f / 16129.f);  // /127^2
  }

  // per-lane role: row (grow), hcol-group (hg), selected scales
  int hg   = q >> 1;
  int grow = q & 1;
  float sclS0 = hg ? sclA[4] : sclA[0];
  float sclS1 = hg ? sclA[5] : sclA[1];
  float sclS2 = hg ? sclA[6] : sclA[2];
  float sclS3 = hg ? sclA[7] : sclA[3];

  // zero h buffers (h0 = 0)
  for (int i = tid; i < 2 * 2 * H8STRIDE; i += 256) ((signed char*)h8)[i] = 0;

  float c_state = 0.f;
  int   arow  = (n >> 2) & 1;            // h row this lane supplies to A
  int   hcol  = wave * 32 + hg * 16 + n; // this lane's hcol
  const int4v ZERO4 = {0, 0, 0, 0};      // loop-invariant MFMA C operand
  int ghcolB = hcol * 8;                 // byte offset within a proj row

  __syncthreads();                       // tokens + h zeros

  // --- depth-2 gx prefetch ----------------------------------------------
  us4 hxA, hxB;
  hxA = *(const us4*)((const char*)proj + (unsigned)(tok_lds[grow][0] + ghcolB));
  hxB = *(const us4*)((const char*)proj + (unsigned)(tok_lds[grow][1] + ghcolB));

#define MFMA(A, B, C) __builtin_amdgcn_mfma_i32_16x16x64_i8(A, B, C, 0, 0, 0)

#define SUBSTEP(RB, HX, TOKB)                                                 \
  {                                                                           \
    int4v Af0 = *(const int4v*)(&h8[RB][arow][q * 16]);                       \
    int4v Af1 = *(const int4v*)(&h8[RB][arow][64 + q * 16]);                  \
    /* hoist gx bf16->f32 off the dequant chain */                            \
    float gx0 = bf2f(HX[0]), gx1 = bf2f(HX[1]);                               \
    float gx2 = bf2f(HX[2]), gx3 = bf2f(HX[3]);                               \
    HX = *(const us4*)((const char*)proj + (unsigned)((TOKB) + ghcolB));      \
    /* 16 MFMAs: f pairs first (c_state needs sf earliest), chunk-chained */  \
    int4v F0 = MFMA(Af0, Bw[1][0], ZERO4);                                    \
    int4v F1 = MFMA(Af0, Bw[5][0], ZERO4);                                    \
    F0 = MFMA(Af1, Bw[1][1], F0);                                             \
    F1 = MFMA(Af1, Bw[5][1], F1);                                             \
    int4v I0 = MFMA(Af0, Bw[0][0], ZERO4);                                    \
    int4v I1 = MFMA(Af0, Bw[4][0], ZERO4);                                    \
    I0 = MFMA(Af1, Bw[0][1], I0);                                             \
    I1 = MFMA(Af1, Bw[4][1], I1);                                             \
    int vf = hg ? F1[0] : F0[0];                                              \
    float g1 = __builtin_fmaf((float)vf, sclS1, gx1);                         \
    float ef = __builtin_amdgcn_exp2f(g1);                                    \
    float sf = __builtin_amdgcn_rcpf(1.f + ef);                               \
    int4v G0 = MFMA(Af0, Bw[2][0], ZERO4);                                    \
    int4v G1 = MFMA(Af0, Bw[6][0], ZERO4);                                    \
    G0 = MFMA(Af1, Bw[2][1], G0);                                             \
    G1 = MFMA(Af1, Bw[6][1], G1);                                             \
    int vi = hg ? I1[0] : I0[0];                                              \
    float g0 = __builtin_fmaf((float)vi, sclS0, gx0);                         \
    float ei = __builtin_amdgcn_exp2f(g0);                                    \
    int4v O0 = MFMA(Af0, Bw[3][0], ZERO4);                                    \
    int4v O1 = MFMA(Af0, Bw[7][0], ZERO4);                                    \
    O0 = MFMA(Af1, Bw[3][1], O0);                                             \
    O1 = MFMA(Af1, Bw[7][1], O1);                                             \
    int vg = hg ? G1[0] : G0[0];                                              \
    float g2 = __builtin_fmaf((float)vg, sclS2, gx2);                         \
    float eg = __builtin_amdgcn_exp2f(fminf(g2, 126.f));                      \
    int vo = hg ? O1[0] : O0[0];                                              \
    float g3 = __builtin_fmaf((float)vo, sclS3, gx3);                         \
    float eo = __builtin_amdgcn_exp2f(g3);                                    \
    float r1 = __builtin_amdgcn_rcpf((1.f + ei) * (1.f + eg));                \
    float sitg = (1.f - eg) * r1;             /* si * tg */                   \
    c_state = sf * c_state + sitg;                                            \
    float ec = __builtin_amdgcn_exp2f(fminf(S_TANH * c_state, 126.f));        \
    float r2 = __builtin_amdgcn_rcpf((1.f + eo) * (1.f + ec));                \
    float hv = (1.f - ec) * r2;               /* tanh(c) * so */              \
    /* magic-constant RNE quant: low byte of (hv*127 + 1.5*2^23) */           \
    float qf = __builtin_fmaf(hv, 127.f, 12582912.f);                         \
    h8[(RB) ^ 1][grow][hcol] = (signed char)__float_as_uint(qf);              \
    BAR_LGKM();                                                               \
  }

  for (int step = 0; step < TSTEPS; step += 2){
    int2v tk = *(const int2v*)(&tok_lds[grow][step + 2]);   // both substeps' toks
    SUBSTEP(0, hxA, tk[0])
    SUBSTEP(1, hxB, tk[1])
  }
#undef SUBSTEP
#undef MFMA

  // --- final linear: out[r0+b][j] = (qh[b]/127) . w_lin[j] + b_lin[j] ---
  // TSTEPS even -> final h is in h8[0]
  if (tid < 2 * NCLS){
    int b = tid / NCLS, j = tid - b * NCLS;
    float s = 0.f;
    const float* wl = w_lin + (long)j * HID;
    #pragma unroll 4
    for (int k = 0; k < HID; ++k)
      s += (float)h8[0][b][k] * wl[k];
    out[(long)(r0 + b) * NCLS + j] = b_lin[j] + s * (1.f / 127.f);
  }
}

// ---------------------------------------------------------------------------
extern "C" void kernel_launch(void* const* d_in, const int* in_sizes, int n_in,
                              void* d_out, int out_size, void* d_ws, size_t ws_size,
                              hipStream_t stream)
{
  const int*   x     = (const int*)d_in[0];
  const float* emb   = (const float*)d_in[1];
  const float* w_ih  = (const float*)d_in[2];
  const float* w_hh  = (const float*)d_in[3];
  const float* b_ih  = (const float*)d_in[4];
  const float* b_hh  = (const float*)d_in[5];
  const float* w_lin = (const float*)d_in[6];
  const float* b_lin = (const float*)d_in[7];
  float*       out   = (float*)d_out;
  unsigned short* proj = (unsigned short*)d_ws;   // [V][512] bf16, ~51.5 MB

  int vblocks = (VOCAB + 63) / 64;   // 786
  emb_proj_kernel<<<dim3(vblocks), dim3(256), 0, stream>>>(
      emb, w_ih, b_ih, b_hh, proj);
  lstm_kernel<<<dim3(BATCH / 2), dim3(256), 0, stream>>>(
      x, w_hh, proj, w_lin, b_lin, out);
}

// Round 5
// 397.522 us; speedup vs baseline: 1.4718x; 1.0032x over previous
//
#include <hip/hip_runtime.h>

#define HID    128
#define GATES  512      // 4*HID
#define EMB    64
#define TSTEPS 1024
#define BATCH  512
#define VOCAB  50257
#define NCLS   28
#define H8STRIDE 160    // h row stride in BYTES (i8 h)
#define TPAD   8        // token row pad (ints)
#define TTAIL  4        // token tail pad: prefetch never needs a clamp

// gate pre-scale folded into proj and w_hh scales: i,f,o -> -log2e; g -> -2log2e
#define S_SIG  (-1.442695041f)
#define S_TANH (-2.885390082f)

typedef __attribute__((ext_vector_type(8))) short short8;   // 8 bf16 = 4 VGPRs
typedef __attribute__((ext_vector_type(4))) float f32x4;
typedef __attribute__((ext_vector_type(4))) unsigned short us4;
typedef __attribute__((ext_vector_type(4))) int int4v;
typedef __attribute__((ext_vector_type(2))) int int2v;

// lgkm-only barrier: LDS visibility without draining global (vmcnt) loads.
#define BAR_LGKM() __asm__ __volatile__("s_waitcnt lgkmcnt(0)\n\ts_barrier" ::: "memory")

static __device__ __forceinline__ float bf2f(unsigned short u){
  union { unsigned int i; float f; } v; v.i = ((unsigned int)u) << 16; return v.f;
}
static __device__ __forceinline__ unsigned short f2bf(float f){
  union { float ff; unsigned int i; } v; v.ff = f;
  unsigned int x = v.i;
  x += 0x7fffu + ((x >> 16) & 1u);   // round-to-nearest-even
  return (unsigned short)(x >> 16);
}

// ---------------------------------------------------------------------------
// Phase 0 (new): one-shot prep. All 786 emb_proj blocks previously re-gathered
// and re-split-converted the SAME w_ih + bias. Materialize the exact per-lane
// A-fragments (pre-swizzled, 64B contiguous per lane) + per-lane bias float4
// once: wprep [32 blk][64 lane][32 u16], biasv [32][64][4 f32]. 164 KB.
// blk = wave*8+i of the consumer; conversion code identical to emb_proj's.
// ---------------------------------------------------------------------------
__global__ __launch_bounds__(64) void wih_prep_kernel(
    const float* __restrict__ w_ih,    // [512][64]
    const float* __restrict__ b_ih,    // [512]
    const float* __restrict__ b_hh,    // [512]
    unsigned short* __restrict__ wprep,
    float* __restrict__ biasv)
{
  int blk  = blockIdx.x;       // 0..31  == wave*8 + i
  int lane = threadIdx.x;      // 0..63
  int n = lane & 15;
  int q = lane >> 4;
  int hc = blk * 4;
  int g = (n & 3) * 128 + hc + (n >> 2);
  const float* wr = w_ih + (long)g * EMB;
  unsigned short* dst = wprep + ((long)blk * 64 + lane) * 32;
  #pragma unroll
  for (int ch = 0; ch < 2; ++ch){
    f32x4 w0 = *(const f32x4*)(wr + ch * 32 + q * 8);
    f32x4 w1 = *(const f32x4*)(wr + ch * 32 + q * 8 + 4);
    #pragma unroll
    for (int j = 0; j < 4; ++j){
      unsigned short h0 = f2bf(w0[j]);
      unsigned short h1 = f2bf(w1[j]);
      dst[ch * 8 + j]          = h0;                       // ahi[ch][j]
      dst[ch * 8 + j + 4]      = h1;                       // ahi[ch][j+4]
      dst[16 + ch * 8 + j]     = f2bf(w0[j] - bf2f(h0));   // alo[ch][j]
      dst[16 + ch * 8 + j + 4] = f2bf(w1[j] - bf2f(h1));   // alo[ch][j+4]
    }
  }
  f32x4 bv;
  #pragma unroll
  for (int r = 0; r < 4; ++r){
    int gb = r * 128 + hc + q;
    bv[r] = b_ih[gb] + b_hh[gb];
  }
  *(f32x4*)(biasv + ((long)blk * 64 + lane) * 4) = bv;
}

// ---------------------------------------------------------------------------
// Phase 1 (fast): same math/layout as the proven emb_proj, but A-fragments and
// bias come from wprep/biasv: 4 coalesced 16B loads + 1 16B bias load per
// i-iter, zero conversion VALU, no scattered w_ih/bias gathers.
// ---------------------------------------------------------------------------
__global__ __launch_bounds__(256) void emb_proj_fast_kernel(
    const float* __restrict__ emb,     // [V][64]
    const unsigned short* __restrict__ wprep,
    const float* __restrict__ biasv,
    unsigned short* __restrict__ proj) // [V][512] interleaved bf16
{
  int wave = threadIdx.x >> 6;         // 0..3
  int lane = threadIdx.x & 63;
  int n = lane & 15;
  int q = lane >> 4;
  long v0 = (long)blockIdx.x * 64;

  // B-operand: emb rows for 4 v-tiles (C-col n -> vrow v0+vt*16+n), split bf16
  short8 bhi[4][2], blo[4][2];
  #pragma unroll
  for (int vt = 0; vt < 4; ++vt){
    long vrow = v0 + vt * 16 + n; if (vrow >= VOCAB) vrow = VOCAB - 1;
    const float* er = emb + vrow * EMB;
    #pragma unroll
    for (int ch = 0; ch < 2; ++ch){
      f32x4 e0 = *(const f32x4*)(er + ch * 32 + q * 8);
      f32x4 e1 = *(const f32x4*)(er + ch * 32 + q * 8 + 4);
      #pragma unroll
      for (int j = 0; j < 4; ++j){
        unsigned short h0 = f2bf(e0[j]);
        bhi[vt][ch][j] = (short)h0;
        blo[vt][ch][j] = (short)f2bf(e0[j] - bf2f(h0));
        unsigned short h1 = f2bf(e1[j]);
        bhi[vt][ch][j + 4] = (short)h1;
        blo[vt][ch][j + 4] = (short)f2bf(e1[j] - bf2f(h1));
      }
    }
  }

  #pragma unroll 1
  for (int i = 0; i < 8; ++i){
    int hc = (wave * 8 + i) * 4;       // hcol group base (4 hcols x 4 types)
    const unsigned short* ab = wprep + ((long)(wave * 8 + i) * 64 + lane) * 32;
    short8 ahi[2], alo[2];
    ahi[0] = *(const short8*)(ab);
    ahi[1] = *(const short8*)(ab + 8);
    alo[0] = *(const short8*)(ab + 16);
    alo[1] = *(const short8*)(ab + 24);
    f32x4 bias = *(const f32x4*)(biasv + ((long)(wave * 8 + i) * 64 + lane) * 4);
    #pragma unroll
    for (int vt = 0; vt < 4; ++vt){
      f32x4 acc = bias;
      #pragma unroll
      for (int ch = 0; ch < 2; ++ch){
        acc = __builtin_amdgcn_mfma_f32_16x16x32_bf16(ahi[ch], bhi[vt][ch], acc, 0, 0, 0);
        acc = __builtin_amdgcn_mfma_f32_16x16x32_bf16(ahi[ch], blo[vt][ch], acc, 0, 0, 0);
        acc = __builtin_amdgcn_mfma_f32_16x16x32_bf16(alo[ch], bhi[vt][ch], acc, 0, 0, 0);
      }
      long v = v0 + vt * 16 + n;
      if (v < VOCAB){
        us4 o;
        #pragma unroll
        for (int r = 0; r < 4; ++r)
          o[r] = f2bf(((r == 2) ? S_TANH : S_SIG) * acc[r]);
        *(us4*)(proj + v * GATES + (hc + q) * 4) = o;   // 8B contiguous store
      }
    }
  }
}

// ---------------------------------------------------------------------------
// Phase 1 (fallback): byte-identical to the proven 442.8 µs version; used only
// if ws_size can't fit wprep/biasv.
// ---------------------------------------------------------------------------
__global__ __launch_bounds__(256) void emb_proj_kernel(
    const float* __restrict__ emb,     // [V][64]
    const float* __restrict__ w_ih,    // [512][64]
    const float* __restrict__ b_ih,    // [512]
    const float* __restrict__ b_hh,    // [512]
    unsigned short* __restrict__ proj) // [V][512] interleaved bf16
{
  int wave = threadIdx.x >> 6;         // 0..3
  int lane = threadIdx.x & 63;
  int n = lane & 15;
  int q = lane >> 4;
  long v0 = (long)blockIdx.x * 64;

  short8 bhi[4][2], blo[4][2];
  #pragma unroll
  for (int vt = 0; vt < 4; ++vt){
    long vrow = v0 + vt * 16 + n; if (vrow >= VOCAB) vrow = VOCAB - 1;
    const float* er = emb + vrow * EMB;
    #pragma unroll
    for (int ch = 0; ch < 2; ++ch){
      f32x4 e0 = *(const f32x4*)(er + ch * 32 + q * 8);
      f32x4 e1 = *(const f32x4*)(er + ch * 32 + q * 8 + 4);
      #pragma unroll
      for (int j = 0; j < 4; ++j){
        unsigned short h0 = f2bf(e0[j]);
        bhi[vt][ch][j] = (short)h0;
        blo[vt][ch][j] = (short)f2bf(e0[j] - bf2f(h0));
        unsigned short h1 = f2bf(e1[j]);
        bhi[vt][ch][j + 4] = (short)h1;
        blo[vt][ch][j + 4] = (short)f2bf(e1[j] - bf2f(h1));
      }
    }
  }

  #pragma unroll 1
  for (int i = 0; i < 8; ++i){
    int hc = (wave * 8 + i) * 4;
    const float* wr = w_ih + (long)((n & 3) * 128 + hc + (n >> 2)) * EMB;
    short8 ahi[2], alo[2];
    #pragma unroll
    for (int ch = 0; ch < 2; ++ch){
      f32x4 w0 = *(const f32x4*)(wr + ch * 32 + q * 8);
      f32x4 w1 = *(const f32x4*)(wr + ch * 32 + q * 8 + 4);
      #pragma unroll
      for (int j = 0; j < 4; ++j){
        unsigned short h0 = f2bf(w0[j]);
        ahi[ch][j] = (short)h0;
        alo[ch][j] = (short)f2bf(w0[j] - bf2f(h0));
        unsigned short h1 = f2bf(w1[j]);
        ahi[ch][j + 4] = (short)h1;
        alo[ch][j + 4] = (short)f2bf(w1[j] - bf2f(h1));
      }
    }
    f32x4 bias;
    #pragma unroll
    for (int r = 0; r < 4; ++r){
      int g = r * 128 + hc + q;
      bias[r] = b_ih[g] + b_hh[g];
    }
    #pragma unroll
    for (int vt = 0; vt < 4; ++vt){
      f32x4 acc = bias;
      #pragma unroll
      for (int ch = 0; ch < 2; ++ch){
        acc = __builtin_amdgcn_mfma_f32_16x16x32_bf16(ahi[ch], bhi[vt][ch], acc, 0, 0, 0);
        acc = __builtin_amdgcn_mfma_f32_16x16x32_bf16(ahi[ch], blo[vt][ch], acc, 0, 0, 0);
        acc = __builtin_amdgcn_mfma_f32_16x16x32_bf16(alo[ch], bhi[vt][ch], acc, 0, 0, 0);
      }
      long v = v0 + vt * 16 + n;
      if (v < VOCAB){
        us4 o;
        #pragma unroll
        for (int r = 0; r < 4; ++r)
          o[r] = f2bf(((r == 2) ? S_TANH : S_SIG) * acc[r]);
        *(us4*)(proj + v * GATES + (hc + q) * 4) = o;
      }
    }
  }
}

// ---------------------------------------------------------------------------
// Phase 2: LSTM recurrence + final linear. FROZEN at the R4 structure
// (measured 340 µs, T_substep 797 cyc). Structural floor analysis: MFMA issue
// per SIMD is invariant at 16 (~326 cyc) for any rows/block split; with
// read(~120) + tail(~150) + barrier(~100) this is within ~10% of floor.
// 256 blocks x 256 threads (4 waves), R=2, 1 block/CU, i8 16x16x64 MFMA,
// per-gate-row max-scaled w_hh, no-dup nonlin, one lgkm barrier/substep.
// ---------------------------------------------------------------------------
__global__ __launch_bounds__(256, 1) void lstm_kernel(
    const int* __restrict__ x,           // [512][1024] int32
    const float* __restrict__ w_hh,      // [512][128] f32
    const unsigned short* __restrict__ proj, // [V][512] bf16 interleaved
    const float* __restrict__ w_lin,     // [28][128] f32
    const float* __restrict__ b_lin,     // [28] f32
    float* __restrict__ out)             // [512][28] f32
{
  __shared__ int   tok_lds[2][TSTEPS + TPAD];   // tok*GATES*2 (byte offsets)
  __shared__ signed char h8[2][2][H8STRIDE];    // [buf][row][hcol] i8 h

  int tid  = threadIdx.x;
  int wave = tid >> 6;          // 0..3
  int lane = tid & 63;
  int n = lane & 15;
  int q = lane >> 4;
  int r0 = blockIdx.x * 2;

  for (int i = tid; i < TSTEPS + TTAIL; i += 256){
    int src = i < TSTEPS ? i : TSTEPS - 1;
    tok_lds[0][i] = x[(long)r0 * TSTEPS + src] * (GATES * 2);
    tok_lds[1][i] = x[(long)(r0 + 1) * TSTEPS + src] * (GATES * 2);
  }

  int4v Bw[8][2];
  float sclA[8];
  #pragma unroll
  for (int t = 0; t < 8; ++t){
    int type = t & 3, hgt = t >> 2;
    int row = type * 128 + wave * 32 + hgt * 16 + n;
    const float* wr = w_hh + (long)row * HID;
    float vals[2][16];
    float m = 0.f;
    #pragma unroll
    for (int ch = 0; ch < 2; ++ch)
      #pragma unroll
      for (int j = 0; j < 16; ++j){
        float v = wr[ch * 64 + q * 16 + j];
        vals[ch][j] = v;
        m = fmaxf(m, fabsf(v));
      }
    m = fmaxf(m, __shfl_xor(m, 16, 64));
    m = fmaxf(m, __shfl_xor(m, 32, 64));
    m = fmaxf(m, 1e-20f);
    float qs = 127.f / m;
    #pragma unroll
    for (int ch = 0; ch < 2; ++ch){
      #pragma unroll
      for (int d = 0; d < 4; ++d){
        int b0 = (int)__builtin_rintf(vals[ch][d * 4 + 0] * qs);
        int b1 = (int)__builtin_rintf(vals[ch][d * 4 + 1] * qs);
        int b2 = (int)__builtin_rintf(vals[ch][d * 4 + 2] * qs);
        int b3 = (int)__builtin_rintf(vals[ch][d * 4 + 3] * qs);
        Bw[t][ch][d] = (b0 & 255) | ((b1 & 255) << 8) | ((b2 & 255) << 16) | (b3 << 24);
      }
    }
    sclA[t] = ((type == 2) ? S_TANH : S_SIG) * m * (1.f / 16129.f);  // /127^2
  }

  int hg   = q >> 1;
  int grow = q & 1;
  float sclS0 = hg ? sclA[4] : sclA[0];
  float sclS1 = hg ? sclA[5] : sclA[1];
  float sclS2 = hg ? sclA[6] : sclA[2];
  float sclS3 = hg ? sclA[7] : sclA[3];

  for (int i = tid; i < 2 * 2 * H8STRIDE; i += 256) ((signed char*)h8)[i] = 0;

  float c_state = 0.f;
  int   arow  = (n >> 2) & 1;
  int   hcol  = wave * 32 + hg * 16 + n;
  const int4v ZERO4 = {0, 0, 0, 0};
  int ghcolB = hcol * 8;

  __syncthreads();

  us4 hxA, hxB;
  hxA = *(const us4*)((const char*)proj + (unsigned)(tok_lds[grow][0] + ghcolB));
  hxB = *(const us4*)((const char*)proj + (unsigned)(tok_lds[grow][1] + ghcolB));

#define MFMA(A, B, C) __builtin_amdgcn_mfma_i32_16x16x64_i8(A, B, C, 0, 0, 0)

#define SUBSTEP(RB, HX, TOKB)                                                 \
  {                                                                           \
    int4v Af0 = *(const int4v*)(&h8[RB][arow][q * 16]);                       \
    int4v Af1 = *(const int4v*)(&h8[RB][arow][64 + q * 16]);                  \
    float gx0 = bf2f(HX[0]), gx1 = bf2f(HX[1]);                               \
    float gx2 = bf2f(HX[2]), gx3 = bf2f(HX[3]);                               \
    HX = *(const us4*)((const char*)proj + (unsigned)((TOKB) + ghcolB));      \
    int4v F0 = MFMA(Af0, Bw[1][0], ZERO4);                                    \
    int4v F1 = MFMA(Af0, Bw[5][0], ZERO4);                                    \
    F0 = MFMA(Af1, Bw[1][1], F0);                                             \
    F1 = MFMA(Af1, Bw[5][1], F1);                                             \
    int4v I0 = MFMA(Af0, Bw[0][0], ZERO4);                                    \
    int4v I1 = MFMA(Af0, Bw[4][0], ZERO4);                                    \
    I0 = MFMA(Af1, Bw[0][1], I0);                                             \
    I1 = MFMA(Af1, Bw[4][1], I1);                                             \
    int vf = hg ? F1[0] : F0[0];                                              \
    float g1 = __builtin_fmaf((float)vf, sclS1, gx1);                         \
    float ef = __builtin_amdgcn_exp2f(g1);                                    \
    float sf = __builtin_amdgcn_rcpf(1.f + ef);                               \
    int4v G0 = MFMA(Af0, Bw[2][0], ZERO4);                                    \
    int4v G1 = MFMA(Af0, Bw[6][0], ZERO4);                                    \
    G0 = MFMA(Af1, Bw[2][1], G0);                                             \
    G1 = MFMA(Af1, Bw[6][1], G1);                                             \
    int vi = hg ? I1[0] : I0[0];                                              \
    float g0 = __builtin_fmaf((float)vi, sclS0, gx0);                         \
    float ei = __builtin_amdgcn_exp2f(g0);                                    \
    int4v O0 = MFMA(Af0, Bw[3][0], ZERO4);                                    \
    int4v O1 = MFMA(Af0, Bw[7][0], ZERO4);                                    \
    O0 = MFMA(Af1, Bw[3][1], O0);                                             \
    O1 = MFMA(Af1, Bw[7][1], O1);                                             \
    int vg = hg ? G1[0] : G0[0];                                              \
    float g2 = __builtin_fmaf((float)vg, sclS2, gx2);                         \
    float eg = __builtin_amdgcn_exp2f(fminf(g2, 126.f));                      \
    int vo = hg ? O1[0] : O0[0];                                              \
    float g3 = __builtin_fmaf((float)vo, sclS3, gx3);                         \
    float eo = __builtin_amdgcn_exp2f(g3);                                    \
    float r1 = __builtin_amdgcn_rcpf((1.f + ei) * (1.f + eg));                \
    float sitg = (1.f - eg) * r1;             /* si * tg */                   \
    c_state = sf * c_state + sitg;                                            \
    float ec = __builtin_amdgcn_exp2f(fminf(S_TANH * c_state, 126.f));        \
    float r2 = __builtin_amdgcn_rcpf((1.f + eo) * (1.f + ec));                \
    float hv = (1.f - ec) * r2;               /* tanh(c) * so */              \
    float qf = __builtin_fmaf(hv, 127.f, 12582912.f);                         \
    h8[(RB) ^ 1][grow][hcol] = (signed char)__float_as_uint(qf);              \
    BAR_LGKM();                                                               \
  }

  for (int step = 0; step < TSTEPS; step += 2){
    int2v tk = *(const int2v*)(&tok_lds[grow][step + 2]);
    SUBSTEP(0, hxA, tk[0])
    SUBSTEP(1, hxB, tk[1])
  }
#undef SUBSTEP
#undef MFMA

  if (tid < 2 * NCLS){
    int b = tid / NCLS, j = tid - b * NCLS;
    float s = 0.f;
    const float* wl = w_lin + (long)j * HID;
    #pragma unroll 4
    for (int k = 0; k < HID; ++k)
      s += (float)h8[0][b][k] * wl[k];
    out[(long)(r0 + b) * NCLS + j] = b_lin[j] + s * (1.f / 127.f);
  }
}

// ---------------------------------------------------------------------------
extern "C" void kernel_launch(void* const* d_in, const int* in_sizes, int n_in,
                              void* d_out, int out_size, void* d_ws, size_t ws_size,
                              hipStream_t stream)
{
  const int*   x     = (const int*)d_in[0];
  const float* emb   = (const float*)d_in[1];
  const float* w_ih  = (const float*)d_in[2];
  const float* w_hh  = (const float*)d_in[3];
  const float* b_ih  = (const float*)d_in[4];
  const float* b_hh  = (const float*)d_in[5];
  const float* w_lin = (const float*)d_in[6];
  const float* b_lin = (const float*)d_in[7];
  float*       out   = (float*)d_out;

  const size_t PROJ_BYTES  = (size_t)VOCAB * GATES * 2;     // 51,463,168
  const size_t WPREP_BYTES = 32 * 64 * 32 * sizeof(unsigned short); // 131,072
  const size_t BIASV_BYTES = 32 * 64 * 4 * sizeof(float);           //  32,768

  unsigned short* proj = (unsigned short*)d_ws;

  int vblocks = (VOCAB + 63) / 64;   // 786
  if (ws_size >= PROJ_BYTES + WPREP_BYTES + BIASV_BYTES){
    unsigned short* wprep = (unsigned short*)((char*)d_ws + PROJ_BYTES);
    float*          biasv = (float*)((char*)d_ws + PROJ_BYTES + WPREP_BYTES);
    wih_prep_kernel<<<dim3(32), dim3(64), 0, stream>>>(
        w_ih, b_ih, b_hh, wprep, biasv);
    emb_proj_fast_kernel<<<dim3(vblocks), dim3(256), 0, stream>>>(
        emb, wprep, biasv, proj);
  } else {
    emb_proj_kernel<<<dim3(vblocks), dim3(256), 0, stream>>>(
        emb, w_ih, b_ih, b_hh, proj);
  }
  lstm_kernel<<<dim3(BATCH / 2), dim3(256), 0, stream>>>(
      x, w_hh, proj, w_lin, b_lin, out);
}

// Round 6
// 392.351 us; speedup vs baseline: 1.4912x; 1.0132x over previous
//
#include <hip/hip_runtime.h>

#define HID    128
#define GATES  512      // 4*HID
#define EMB    64
#define TSTEPS 1024
#define BATCH  512
#define VOCAB  50257
#define NCLS   28
#define H8STRIDE 160    // h row stride in BYTES (i8 h)
#define TPAD   8        // token row pad (ints)
#define TTAIL  4        // token tail pad: prefetch never needs a clamp

// gate pre-scale folded into proj and w_hh scales: i,f,o -> -log2e; g -> -2log2e
#define S_SIG  (-1.442695041f)
#define S_TANH (-2.885390082f)

typedef __attribute__((ext_vector_type(8))) short short8;   // 8 bf16 = 4 VGPRs
typedef __attribute__((ext_vector_type(4))) float f32x4;
typedef __attribute__((ext_vector_type(4))) unsigned short us4;
typedef __attribute__((ext_vector_type(4))) int int4v;
typedef __attribute__((ext_vector_type(2))) int int2v;

// lgkm-only barrier: LDS visibility without draining global (vmcnt) loads.
#define BAR_LGKM() __asm__ __volatile__("s_waitcnt lgkmcnt(0)\n\ts_barrier" ::: "memory")

static __device__ __forceinline__ float bf2f(unsigned short u){
  union { unsigned int i; float f; } v; v.i = ((unsigned int)u) << 16; return v.f;
}
static __device__ __forceinline__ unsigned short f2bf(float f){
  union { float ff; unsigned int i; } v; v.ff = f;
  unsigned int x = v.i;
  x += 0x7fffu + ((x >> 16) & 1u);   // round-to-nearest-even
  return (unsigned short)(x >> 16);
}

// ---------------------------------------------------------------------------
// Phase 0: one-shot prep (kept from R5). Per-lane A-fragments + bias float4.
// ---------------------------------------------------------------------------
__global__ __launch_bounds__(64) void wih_prep_kernel(
    const float* __restrict__ w_ih,    // [512][64]
    const float* __restrict__ b_ih,    // [512]
    const float* __restrict__ b_hh,    // [512]
    unsigned short* __restrict__ wprep,
    float* __restrict__ biasv)
{
  int blk  = blockIdx.x;       // 0..31  == wave*8 + i
  int lane = threadIdx.x;      // 0..63
  int n = lane & 15;
  int q = lane >> 4;
  int hc = blk * 4;
  int g = (n & 3) * 128 + hc + (n >> 2);
  const float* wr = w_ih + (long)g * EMB;
  unsigned short* dst = wprep + ((long)blk * 64 + lane) * 32;
  #pragma unroll
  for (int ch = 0; ch < 2; ++ch){
    f32x4 w0 = *(const f32x4*)(wr + ch * 32 + q * 8);
    f32x4 w1 = *(const f32x4*)(wr + ch * 32 + q * 8 + 4);
    #pragma unroll
    for (int j = 0; j < 4; ++j){
      unsigned short h0 = f2bf(w0[j]);
      unsigned short h1 = f2bf(w1[j]);
      dst[ch * 8 + j]          = h0;                       // ahi[ch][j]
      dst[ch * 8 + j + 4]      = h1;                       // ahi[ch][j+4]
      dst[16 + ch * 8 + j]     = f2bf(w0[j] - bf2f(h0));   // alo[ch][j]
      dst[16 + ch * 8 + j + 4] = f2bf(w1[j] - bf2f(h1));   // alo[ch][j+4]
    }
  }
  f32x4 bv;
  #pragma unroll
  for (int r = 0; r < 4; ++r){
    int gb = r * 128 + hc + q;
    bv[r] = b_ih[gb] + b_hh[gb];
  }
  *(f32x4*)(biasv + ((long)blk * 64 + lane) * 4) = bv;
}

// ---------------------------------------------------------------------------
// Phase 1 (v3): SAME math as R5-fast, but the MFMA fragments go to a 64 KB
// LDS stage (XOR-swizzled: byte ^= (row&7)<<4, involution on both sides),
// and global stores are rebuilt as ONE COMPLETE 1 KB proj row per wave-store
// (lane l -> bytes l*16..l*16+16). Every 128B sector is written whole in one
// instruction -> no partial-sector eviction / RMW write amplification (the
// R2..R5-invariant ~45 µs cost: per-lane v-scatter wrote 32B/sector spread
// across the kernel's lifetime, overflowing L2's 4MB with partial sectors).
// ---------------------------------------------------------------------------
__global__ __launch_bounds__(256) void emb_proj_fast_kernel(
    const float* __restrict__ emb,     // [V][64]
    const unsigned short* __restrict__ wprep,
    const float* __restrict__ biasv,
    unsigned short* __restrict__ proj) // [V][512] interleaved bf16
{
  __shared__ unsigned short stage[64][512];   // 64 v-rows x 1KB

  int wave = threadIdx.x >> 6;         // 0..3
  int lane = threadIdx.x & 63;
  int n = lane & 15;
  int q = lane >> 4;
  long v0 = (long)blockIdx.x * 64;

  // B-operand: emb rows for 4 v-tiles (C-col n -> vrow v0+vt*16+n), split bf16
  short8 bhi[4][2], blo[4][2];
  #pragma unroll
  for (int vt = 0; vt < 4; ++vt){
    long vrow = v0 + vt * 16 + n; if (vrow >= VOCAB) vrow = VOCAB - 1;
    const float* er = emb + vrow * EMB;
    #pragma unroll
    for (int ch = 0; ch < 2; ++ch){
      f32x4 e0 = *(const f32x4*)(er + ch * 32 + q * 8);
      f32x4 e1 = *(const f32x4*)(er + ch * 32 + q * 8 + 4);
      #pragma unroll
      for (int j = 0; j < 4; ++j){
        unsigned short h0 = f2bf(e0[j]);
        bhi[vt][ch][j] = (short)h0;
        blo[vt][ch][j] = (short)f2bf(e0[j] - bf2f(h0));
        unsigned short h1 = f2bf(e1[j]);
        bhi[vt][ch][j + 4] = (short)h1;
        blo[vt][ch][j + 4] = (short)f2bf(e1[j] - bf2f(h1));
      }
    }
  }

  #pragma unroll 1
  for (int i = 0; i < 8; ++i){
    int hc = (wave * 8 + i) * 4;       // hcol group base (4 hcols x 4 types)
    const unsigned short* ab = wprep + ((long)(wave * 8 + i) * 64 + lane) * 32;
    short8 ahi[2], alo[2];
    ahi[0] = *(const short8*)(ab);
    ahi[1] = *(const short8*)(ab + 8);
    alo[0] = *(const short8*)(ab + 16);
    alo[1] = *(const short8*)(ab + 24);
    f32x4 bias = *(const f32x4*)(biasv + ((long)(wave * 8 + i) * 64 + lane) * 4);
    #pragma unroll
    for (int vt = 0; vt < 4; ++vt){
      f32x4 acc = bias;
      #pragma unroll
      for (int ch = 0; ch < 2; ++ch){
        acc = __builtin_amdgcn_mfma_f32_16x16x32_bf16(ahi[ch], bhi[vt][ch], acc, 0, 0, 0);
        acc = __builtin_amdgcn_mfma_f32_16x16x32_bf16(ahi[ch], blo[vt][ch], acc, 0, 0, 0);
        acc = __builtin_amdgcn_mfma_f32_16x16x32_bf16(alo[ch], bhi[vt][ch], acc, 0, 0, 0);
      }
      us4 o;
      #pragma unroll
      for (int r = 0; r < 4; ++r)
        o[r] = f2bf(((r == 2) ? S_TANH : S_SIG) * acc[r]);
      // swizzled LDS stage write: row = vt*16+n, col-bytes (hc+q)*8
      int row = vt * 16 + n;
      int cb  = (hc + q) * 8;
      int sw  = (n & 7) << 4;            // row&7 == n&7 (vt*16 ≡ 0 mod 8)
      *(us4*)((char*)(&stage[0][0]) + row * 1024 + (cb ^ sw)) = o;
    }
  }
  __syncthreads();

  // readout: wave w stores rows w*16..w*16+15; one full 1KB row per instr
  #pragma unroll
  for (int rr = 0; rr < 16; ++rr){
    int row = wave * 16 + rr;
    long v = v0 + row;
    if (v < VOCAB){
      int sw = (row & 7) << 4;
      int4v val = *(const int4v*)((const char*)(&stage[0][0])
                                  + row * 1024 + ((lane * 16) ^ sw));
      *(int4v*)((char*)proj + v * 1024 + lane * 16) = val;
    }
  }
}

// ---------------------------------------------------------------------------
// Phase 1 (fallback): byte-identical to the proven 442.8 µs version; used only
// if ws_size can't fit wprep/biasv.
// ---------------------------------------------------------------------------
__global__ __launch_bounds__(256) void emb_proj_kernel(
    const float* __restrict__ emb,     // [V][64]
    const float* __restrict__ w_ih,    // [512][64]
    const float* __restrict__ b_ih,    // [512]
    const float* __restrict__ b_hh,    // [512]
    unsigned short* __restrict__ proj) // [V][512] interleaved bf16
{
  int wave = threadIdx.x >> 6;         // 0..3
  int lane = threadIdx.x & 63;
  int n = lane & 15;
  int q = lane >> 4;
  long v0 = (long)blockIdx.x * 64;

  short8 bhi[4][2], blo[4][2];
  #pragma unroll
  for (int vt = 0; vt < 4; ++vt){
    long vrow = v0 + vt * 16 + n; if (vrow >= VOCAB) vrow = VOCAB - 1;
    const float* er = emb + vrow * EMB;
    #pragma unroll
    for (int ch = 0; ch < 2; ++ch){
      f32x4 e0 = *(const f32x4*)(er + ch * 32 + q * 8);
      f32x4 e1 = *(const f32x4*)(er + ch * 32 + q * 8 + 4);
      #pragma unroll
      for (int j = 0; j < 4; ++j){
        unsigned short h0 = f2bf(e0[j]);
        bhi[vt][ch][j] = (short)h0;
        blo[vt][ch][j] = (short)f2bf(e0[j] - bf2f(h0));
        unsigned short h1 = f2bf(e1[j]);
        bhi[vt][ch][j + 4] = (short)h1;
        blo[vt][ch][j + 4] = (short)f2bf(e1[j] - bf2f(h1));
      }
    }
  }

  #pragma unroll 1
  for (int i = 0; i < 8; ++i){
    int hc = (wave * 8 + i) * 4;
    const float* wr = w_ih + (long)((n & 3) * 128 + hc + (n >> 2)) * EMB;
    short8 ahi[2], alo[2];
    #pragma unroll
    for (int ch = 0; ch < 2; ++ch){
      f32x4 w0 = *(const f32x4*)(wr + ch * 32 + q * 8);
      f32x4 w1 = *(const f32x4*)(wr + ch * 32 + q * 8 + 4);
      #pragma unroll
      for (int j = 0; j < 4; ++j){
        unsigned short h0 = f2bf(w0[j]);
        ahi[ch][j] = (short)h0;
        alo[ch][j] = (short)f2bf(w0[j] - bf2f(h0));
        unsigned short h1 = f2bf(w1[j]);
        ahi[ch][j + 4] = (short)h1;
        alo[ch][j + 4] = (short)f2bf(w1[j] - bf2f(h1));
      }
    }
    f32x4 bias;
    #pragma unroll
    for (int r = 0; r < 4; ++r){
      int g = r * 128 + hc + q;
      bias[r] = b_ih[g] + b_hh[g];
    }
    #pragma unroll
    for (int vt = 0; vt < 4; ++vt){
      f32x4 acc = bias;
      #pragma unroll
      for (int ch = 0; ch < 2; ++ch){
        acc = __builtin_amdgcn_mfma_f32_16x16x32_bf16(ahi[ch], bhi[vt][ch], acc, 0, 0, 0);
        acc = __builtin_amdgcn_mfma_f32_16x16x32_bf16(ahi[ch], blo[vt][ch], acc, 0, 0, 0);
        acc = __builtin_amdgcn_mfma_f32_16x16x32_bf16(alo[ch], bhi[vt][ch], acc, 0, 0, 0);
      }
      long v = v0 + vt * 16 + n;
      if (v < VOCAB){
        us4 o;
        #pragma unroll
        for (int r = 0; r < 4; ++r)
          o[r] = f2bf(((r == 2) ? S_TANH : S_SIG) * acc[r]);
        *(us4*)(proj + v * GATES + (hc + q) * 4) = o;
      }
    }
  }
}

// ---------------------------------------------------------------------------
// Phase 2: LSTM recurrence + final linear. FROZEN (measured 340-342 µs,
// T_substep ~800 cyc). Byte-identical to R4/R5 — this dispatch is the control.
// ---------------------------------------------------------------------------
__global__ __launch_bounds__(256, 1) void lstm_kernel(
    const int* __restrict__ x,           // [512][1024] int32
    const float* __restrict__ w_hh,      // [512][128] f32
    const unsigned short* __restrict__ proj, // [V][512] bf16 interleaved
    const float* __restrict__ w_lin,     // [28][128] f32
    const float* __restrict__ b_lin,     // [28] f32
    float* __restrict__ out)             // [512][28] f32
{
  __shared__ int   tok_lds[2][TSTEPS + TPAD];   // tok*GATES*2 (byte offsets)
  __shared__ signed char h8[2][2][H8STRIDE];    // [buf][row][hcol] i8 h

  int tid  = threadIdx.x;
  int wave = tid >> 6;          // 0..3
  int lane = tid & 63;
  int n = lane & 15;
  int q = lane >> 4;
  int r0 = blockIdx.x * 2;

  for (int i = tid; i < TSTEPS + TTAIL; i += 256){
    int src = i < TSTEPS ? i : TSTEPS - 1;
    tok_lds[0][i] = x[(long)r0 * TSTEPS + src] * (GATES * 2);
    tok_lds[1][i] = x[(long)(r0 + 1) * TSTEPS + src] * (GATES * 2);
  }

  int4v Bw[8][2];
  float sclA[8];
  #pragma unroll
  for (int t = 0; t < 8; ++t){
    int type = t & 3, hgt = t >> 2;
    int row = type * 128 + wave * 32 + hgt * 16 + n;
    const float* wr = w_hh + (long)row * HID;
    float vals[2][16];
    float m = 0.f;
    #pragma unroll
    for (int ch = 0; ch < 2; ++ch)
      #pragma unroll
      for (int j = 0; j < 16; ++j){
        float v = wr[ch * 64 + q * 16 + j];
        vals[ch][j] = v;
        m = fmaxf(m, fabsf(v));
      }
    m = fmaxf(m, __shfl_xor(m, 16, 64));
    m = fmaxf(m, __shfl_xor(m, 32, 64));
    m = fmaxf(m, 1e-20f);
    float qs = 127.f / m;
    #pragma unroll
    for (int ch = 0; ch < 2; ++ch){
      #pragma unroll
      for (int d = 0; d < 4; ++d){
        int b0 = (int)__builtin_rintf(vals[ch][d * 4 + 0] * qs);
        int b1 = (int)__builtin_rintf(vals[ch][d * 4 + 1] * qs);
        int b2 = (int)__builtin_rintf(vals[ch][d * 4 + 2] * qs);
        int b3 = (int)__builtin_rintf(vals[ch][d * 4 + 3] * qs);
        Bw[t][ch][d] = (b0 & 255) | ((b1 & 255) << 8) | ((b2 & 255) << 16) | (b3 << 24);
      }
    }
    sclA[t] = ((type == 2) ? S_TANH : S_SIG) * m * (1.f / 16129.f);  // /127^2
  }

  int hg   = q >> 1;
  int grow = q & 1;
  float sclS0 = hg ? sclA[4] : sclA[0];
  float sclS1 = hg ? sclA[5] : sclA[1];
  float sclS2 = hg ? sclA[6] : sclA[2];
  float sclS3 = hg ? sclA[7] : sclA[3];

  for (int i = tid; i < 2 * 2 * H8STRIDE; i += 256) ((signed char*)h8)[i] = 0;

  float c_state = 0.f;
  int   arow  = (n >> 2) & 1;
  int   hcol  = wave * 32 + hg * 16 + n;
  const int4v ZERO4 = {0, 0, 0, 0};
  int ghcolB = hcol * 8;

  __syncthreads();

  us4 hxA, hxB;
  hxA = *(const us4*)((const char*)proj + (unsigned)(tok_lds[grow][0] + ghcolB));
  hxB = *(const us4*)((const char*)proj + (unsigned)(tok_lds[grow][1] + ghcolB));

#define MFMA(A, B, C) __builtin_amdgcn_mfma_i32_16x16x64_i8(A, B, C, 0, 0, 0)

#define SUBSTEP(RB, HX, TOKB)                                                 \
  {                                                                           \
    int4v Af0 = *(const int4v*)(&h8[RB][arow][q * 16]);                       \
    int4v Af1 = *(const int4v*)(&h8[RB][arow][64 + q * 16]);                  \
    float gx0 = bf2f(HX[0]), gx1 = bf2f(HX[1]);                               \
    float gx2 = bf2f(HX[2]), gx3 = bf2f(HX[3]);                               \
    HX = *(const us4*)((const char*)proj + (unsigned)((TOKB) + ghcolB));      \
    int4v F0 = MFMA(Af0, Bw[1][0], ZERO4);                                    \
    int4v F1 = MFMA(Af0, Bw[5][0], ZERO4);                                    \
    F0 = MFMA(Af1, Bw[1][1], F0);                                             \
    F1 = MFMA(Af1, Bw[5][1], F1);                                             \
    int4v I0 = MFMA(Af0, Bw[0][0], ZERO4);                                    \
    int4v I1 = MFMA(Af0, Bw[4][0], ZERO4);                                    \
    I0 = MFMA(Af1, Bw[0][1], I0);                                             \
    I1 = MFMA(Af1, Bw[4][1], I1);                                             \
    int vf = hg ? F1[0] : F0[0];                                              \
    float g1 = __builtin_fmaf((float)vf, sclS1, gx1);                         \
    float ef = __builtin_amdgcn_exp2f(g1);                                    \
    float sf = __builtin_amdgcn_rcpf(1.f + ef);                               \
    int4v G0 = MFMA(Af0, Bw[2][0], ZERO4);                                    \
    int4v G1 = MFMA(Af0, Bw[6][0], ZERO4);                                    \
    G0 = MFMA(Af1, Bw[2][1], G0);                                             \
    G1 = MFMA(Af1, Bw[6][1], G1);                                             \
    int vi = hg ? I1[0] : I0[0];                                              \
    float g0 = __builtin_fmaf((float)vi, sclS0, gx0);                         \
    float ei = __builtin_amdgcn_exp2f(g0);                                    \
    int4v O0 = MFMA(Af0, Bw[3][0], ZERO4);                                    \
    int4v O1 = MFMA(Af0, Bw[7][0], ZERO4);                                    \
    O0 = MFMA(Af1, Bw[3][1], O0);                                             \
    O1 = MFMA(Af1, Bw[7][1], O1);                                             \
    int vg = hg ? G1[0] : G0[0];                                              \
    float g2 = __builtin_fmaf((float)vg, sclS2, gx2);                         \
    float eg = __builtin_amdgcn_exp2f(fminf(g2, 126.f));                      \
    int vo = hg ? O1[0] : O0[0];                                              \
    float g3 = __builtin_fmaf((float)vo, sclS3, gx3);                         \
    float eo = __builtin_amdgcn_exp2f(g3);                                    \
    float r1 = __builtin_amdgcn_rcpf((1.f + ei) * (1.f + eg));                \
    float sitg = (1.f - eg) * r1;             /* si * tg */                   \
    c_state = sf * c_state + sitg;                                            \
    float ec = __builtin_amdgcn_exp2f(fminf(S_TANH * c_state, 126.f));        \
    float r2 = __builtin_amdgcn_rcpf((1.f + eo) * (1.f + ec));                \
    float hv = (1.f - ec) * r2;               /* tanh(c) * so */              \
    float qf = __builtin_fmaf(hv, 127.f, 12582912.f);                         \
    h8[(RB) ^ 1][grow][hcol] = (signed char)__float_as_uint(qf);              \
    BAR_LGKM();                                                               \
  }

  for (int step = 0; step < TSTEPS; step += 2){
    int2v tk = *(const int2v*)(&tok_lds[grow][step + 2]);
    SUBSTEP(0, hxA, tk[0])
    SUBSTEP(1, hxB, tk[1])
  }
#undef SUBSTEP
#undef MFMA

  if (tid < 2 * NCLS){
    int b = tid / NCLS, j = tid - b * NCLS;
    float s = 0.f;
    const float* wl = w_lin + (long)j * HID;
    #pragma unroll 4
    for (int k = 0; k < HID; ++k)
      s += (float)h8[0][b][k] * wl[k];
    out[(long)(r0 + b) * NCLS + j] = b_lin[j] + s * (1.f / 127.f);
  }
}

// ---------------------------------------------------------------------------
extern "C" void kernel_launch(void* const* d_in, const int* in_sizes, int n_in,
                              void* d_out, int out_size, void* d_ws, size_t ws_size,
                              hipStream_t stream)
{
  const int*   x     = (const int*)d_in[0];
  const float* emb   = (const float*)d_in[1];
  const float* w_ih  = (const float*)d_in[2];
  const float* w_hh  = (const float*)d_in[3];
  const float* b_ih  = (const float*)d_in[4];
  const float* b_hh  = (const float*)d_in[5];
  const float* w_lin = (const float*)d_in[6];
  const float* b_lin = (const float*)d_in[7];
  float*       out   = (float*)d_out;

  const size_t PROJ_BYTES  = (size_t)VOCAB * GATES * 2;     // 51,463,168
  const size_t WPREP_BYTES = 32 * 64 * 32 * sizeof(unsigned short); // 131,072
  const size_t BIASV_BYTES = 32 * 64 * 4 * sizeof(float);           //  32,768

  unsigned short* proj = (unsigned short*)d_ws;

  int vblocks = (VOCAB + 63) / 64;   // 786
  if (ws_size >= PROJ_BYTES + WPREP_BYTES + BIASV_BYTES){
    unsigned short* wprep = (unsigned short*)((char*)d_ws + PROJ_BYTES);
    float*          biasv = (float*)((char*)d_ws + PROJ_BYTES + WPREP_BYTES);
    wih_prep_kernel<<<dim3(32), dim3(64), 0, stream>>>(
        w_ih, b_ih, b_hh, wprep, biasv);
    emb_proj_fast_kernel<<<dim3(vblocks), dim3(256), 0, stream>>>(
        emb, wprep, biasv, proj);
  } else {
    emb_proj_kernel<<<dim3(vblocks), dim3(256), 0, stream>>>(
        emb, w_ih, b_ih, b_hh, proj);
  }
  lstm_kernel<<<dim3(BATCH / 2), dim3(256), 0, stream>>>(
      x, w_hh, proj, w_lin, b_lin, out);
}